// Round 13
// baseline (154.889 us; speedup 1.0000x reference)
//
#include <hip/hip_runtime.h>

// Fused axial dual-branch attention, bf16 split-precision MFMA. One block per N.
// R16 = R15 structure, two convoys deleted via LDS un-aliasing (no chain touched):
//   Ah/Al moved OUT of the PT region (+9216 B LDS) =>
//   (a) stage-A2 merges into gram0 phase (Ah/Al dead after Q1; disjoint regions;
//       8 splitpk + 2 b128 stores on a 16-MFMA phase ~ zero chain growth),
//   (b) Q2 merges into pv1 phase (S5 orders gram1's QP reads before Q2's writes;
//       pv1 reads PT/VH only -> two independent chains overlap in one phase).
// Barriers 11 -> 9, phases 12 -> 10; inner kernels byte-identical to R15.
// Cost: LDS 30976 -> 40192 => 4 blocks/CU cap (was 5). Measured occupancy 39%
// (~3.1 blocks avg) < cap => should not bind. WATCH occupancy in counters.
// (R12 resubmit: 9th GPUAcquisitionTimeout — no data; kernel unchanged.)
// Model (R12-R15): MfmaUtil x dur == ~1163 (MFMA work fixed); time = per-phase
// serial chains x convoy count. Falsified: LDS-BW (R13), P-in-reg/shuffle (R14).
// PT: 128 t x 64 s, stride 64 u16; 8B units swizzled u' = u ^ (2*(t&7)).
// Wave w: gram s-tile [64h+16w,+16) -> PT half; PV t-chunk [32w,+32), K=64/half.
// Frags (HW-verified): A[m=lane&15][k=quad*8+j]; B[k=quad*8+j][n=lane&15];
// D row=(lane>>4)*4+reg, col=lane&15.
// Lessons: R5vsR8 occupancy>barriers; R6/R11 don't over-constrain allocator;
// R13 op cuts don't move latency-bound time; R14 shuffles ARE LDS ops.

typedef __attribute__((ext_vector_type(8))) short bh8;
typedef __attribute__((ext_vector_type(4))) float f32x4;
typedef unsigned short u16;
typedef unsigned int u32;

#define MFMA16(a,b,c) __builtin_amdgcn_mfma_f32_16x16x32_bf16(a,b,c,0,0,0)

#define AIMG_ST 72    // u16 (144 B rows)
#define QP_ST   40    // u16 (80 B rows)
#define VH_ST   136   // u16 (272 B rows)
#define PT_ST   64    // u16 (128 B rows, XOR-swizzled 8B units, no pad)

#define OFF_PT   0        // 128x64x2 = 16384 (VIN aliases inside; dead before PT use)
#define OFF_VIN  9216     // 32x72x2 = 4608, inside PT span (disjoint lifetime)
#define OFF_AH   16384    // 4608 — UN-ALIASED (enables A2-stage + Q2 phase merges)
#define OFF_AL   20992    // 4608
#define OFF_QP   25600    // 128x40x2 = 10240
#define OFF_VH   35840    // 16x136x2 = 4352
#define LDS_TOT  40192    // x4 blocks = 157 KB <= 160 KB -> 4 blocks/CU

// ---- fast numeric helpers (guarded HW builtins, safe fallbacks) ----
__device__ __forceinline__ u32 cvtpk_rn(float f0, float f1) {
#if __has_builtin(__builtin_amdgcn_cvt_pk_bf16_f32)
    auto h = __builtin_amdgcn_cvt_pk_bf16_f32(f0, f1);
    u32 r; __builtin_memcpy(&r, &h, sizeof(r)); return r;
#else
    return ((__float_as_uint(f0) + 0x8000u) >> 16) |
           ((__float_as_uint(f1) + 0x8000u) & 0xFFFF0000u);
#endif
}
__device__ __forceinline__ float fexp2(float x) {
#if __has_builtin(__builtin_amdgcn_exp2f)
    return __builtin_amdgcn_exp2f(x);
#else
    return exp2f(x);
#endif
}
__device__ __forceinline__ float frcp(float x) {
#if __has_builtin(__builtin_amdgcn_rcpf)
    return __builtin_amdgcn_rcpf(x);
#else
    return 1.0f / x;
#endif
}
// hi = trunc-bf16 pair (1 v_perm), lo = RN-bf16(residual) pair
__device__ __forceinline__ void splitpk(float f0, float f1, u32& hp, u32& lp) {
    u32 u0 = __float_as_uint(f0), u1 = __float_as_uint(f1);
    hp = __builtin_amdgcn_perm(u1, u0, 0x07060302u);   // [u0.hi16 | u1.hi16]
    float r0 = f0 - __uint_as_float(u0 & 0xFFFF0000u);
    float r1 = f1 - __uint_as_float(u1 & 0xFFFF0000u);
    lp = cvtpk_rn(r0, r1);
}
__device__ __forceinline__ void split3(float f, u16& h, u16& l) {
    u32 u = __float_as_uint(f);
    u32 hf = u & 0xFFFF0000u;
    float r = f - __uint_as_float(hf);
    h = (u16)(hf >> 16);
    l = (u16)((__float_as_uint(r) + 0x8000u) >> 16);
}
__device__ __forceinline__ u16 rnbf(float f) {
    return (u16)((__float_as_uint(f) + 0x8000u) >> 16);
}
__device__ __forceinline__ float lrelu(float x) { return x > 0.f ? x : 0.2f * x; }

// ws u16 layout: [WqH 4096][WqL 4096][WkH 4096][WkL 4096 (unused)]
// Wq pre-scaled by 0.5*sqrt(log2 e) so Gram is natively log2e-scaled for exp2.
__global__ void split_w_kernel(const float* __restrict__ Wq,
                               const float* __restrict__ Wk,
                               u16* __restrict__ ws)
{
    const int i = blockIdx.x * 256 + threadIdx.x;
    const int j = i & 4095;
    const float scale = (i < 4096) ? 0.6005612043932249f : 1.0f;
    const float f = ((i < 4096) ? Wq[j] : Wk[j]) * scale;
    const int base = (i < 4096) ? 0 : 8192;
    u16 h, l; split3(f, h, l);
    ws[base + j] = h;
    ws[base + 4096 + j] = l;
}

#define WOFF(n, ks) (((n)*16 + lid)*64 + (ks)*32 + quad*8)

// Q GEMM: 3-term hi/lo split, 12 MFMA (scale pre-folded into weights), -> Qpack.
__device__ __forceinline__ void gemm_q(const u16* Ah, const u16* Al,
                                       const u16* wsu,
                                       u16* qp, int miQ, int niA, int lid, int quad)
{
    const bh8 h0a = *(const bh8*)(wsu +        WOFF(niA+0,0));
    const bh8 h0b = *(const bh8*)(wsu +        WOFF(niA+0,1));
    const bh8 h1a = *(const bh8*)(wsu +        WOFF(niA+1,0));
    const bh8 h1b = *(const bh8*)(wsu +        WOFF(niA+1,1));
    const bh8 l0a = *(const bh8*)(wsu + 4096 + WOFF(niA+0,0));
    const bh8 l0b = *(const bh8*)(wsu + 4096 + WOFF(niA+0,1));
    const bh8 l1a = *(const bh8*)(wsu + 4096 + WOFF(niA+1,0));
    const bh8 l1b = *(const bh8*)(wsu + 4096 + WOFF(niA+1,1));
    const int offA = (miQ*16 + lid)*AIMG_ST + quad*8;
    bh8 ah0 = *(const bh8*)(Ah + offA);
    bh8 ah1 = *(const bh8*)(Ah + offA + 32);
    bh8 al0 = *(const bh8*)(Al + offA);
    bh8 al1 = *(const bh8*)(Al + offA + 32);
    f32x4 acc0 = {0.f,0.f,0.f,0.f}, acc1 = {0.f,0.f,0.f,0.f};
    acc0 = MFMA16(ah0, h0a, acc0); acc0 = MFMA16(ah0, l0a, acc0); acc0 = MFMA16(al0, h0a, acc0);
    acc0 = MFMA16(ah1, h0b, acc0); acc0 = MFMA16(ah1, l0b, acc0); acc0 = MFMA16(al1, h0b, acc0);
    acc1 = MFMA16(ah0, h1a, acc1); acc1 = MFMA16(ah0, l1a, acc1); acc1 = MFMA16(al0, h1a, acc1);
    acc1 = MFMA16(ah1, h1b, acc1); acc1 = MFMA16(ah1, l1b, acc1); acc1 = MFMA16(al1, h1b, acc1);
    #pragma unroll
    for (int r = 0; r < 4; ++r) {
        const int l = miQ*16 + quad*4 + r;
        const int d = l >> 1;
        const int sbase = (l & 1) << 6;
        const int s0 = sbase + (niA + 0)*16 + lid;
        const int s1 = sbase + (niA + 1)*16 + lid;
        u32 hp, lp;
        splitpk(acc0[r], acc1[r], hp, lp);
        qp[s0*QP_ST + d]      = (u16)hp;
        qp[s0*QP_ST + 16 + d] = (u16)lp;
        qp[s1*QP_ST + d]      = (u16)(hp >> 16);
        qp[s1*QP_ST + 16 + d] = (u16)(lp >> 16);
    }
}

// V GEMM: single-term bf16, 4 MFMA, writes VH[d][s].
__device__ __forceinline__ void gemm_v(const u16* Vin, const u16* wsu,
                                       u16* vh, int miQ, int niA, int lid, int quad)
{
    const bh8 h0a = *(const bh8*)(wsu + 8192 + WOFF(niA+0,0));
    const bh8 h0b = *(const bh8*)(wsu + 8192 + WOFF(niA+0,1));
    const bh8 h1a = *(const bh8*)(wsu + 8192 + WOFF(niA+1,0));
    const bh8 h1b = *(const bh8*)(wsu + 8192 + WOFF(niA+1,1));
    const int offA = (miQ*16 + lid)*AIMG_ST + quad*8;
    bh8 ah0 = *(const bh8*)(Vin + offA);
    bh8 ah1 = *(const bh8*)(Vin + offA + 32);
    f32x4 acc0 = {0.f,0.f,0.f,0.f}, acc1 = {0.f,0.f,0.f,0.f};
    acc0 = MFMA16(ah0, h0a, acc0); acc0 = MFMA16(ah1, h0b, acc0);
    acc1 = MFMA16(ah0, h1a, acc1); acc1 = MFMA16(ah1, h1b, acc1);
    #pragma unroll
    for (int r = 0; r < 4; ++r) {
        const int l = miQ*16 + quad*4 + r;
        const int d = l >> 1;
        const int sbase = (l & 1) << 6;
        vh[d*VH_ST + sbase + (niA + 0)*16 + lid] = rnbf(acc0[r]);
        vh[d*VH_ST + sbase + (niA + 1)*16 + lid] = rnbf(acc1[r]);
    }
}

// Gram + wave-local softmax (exp2, scale pre-folded) for s-tile [64h+16w, +16).
// P^T write: one 8B unit per (lane,ti), unit index (4w+quad) ^ (2*(t&7)), t&7==lid&7.
__device__ __forceinline__ void gram_pt(const u16* Qp, u16* PT, int h,
                                        int w, int lid, int quad)
{
    const u16* arow = Qp + (h*64 + 16*w + lid)*QP_ST;
    bh8 a1 = *(const bh8*)(arow + quad*8);                        // [Qh;Ql]
    bh8 t  = *(const bh8*)(arow + ((quad >= 2) ? (quad-2)*8 : 0));
    bh8 zz = t ^ t;
    bh8 a2 = (quad < 2) ? zz : t;                                 // [0;Qh]
    f32x4 g[8];
    #pragma unroll
    for (int ti = 0; ti < 8; ++ti) {
        const u16* brow = Qp + (ti*16 + lid)*QP_ST;
        bh8 b1 = *(const bh8*)(brow + (quad & 1)*8);              // [Qh;Qh]
        bh8 b2 = *(const bh8*)(brow + quad*8);                    // [Qh;Ql]
        f32x4 acc = {0.f,0.f,0.f,0.f};
        acc = MFMA16(a1, b1, acc);
        acc = MFMA16(a2, b2, acc);
        g[ti] = acc;
    }
    float inv[4];
    #pragma unroll
    for (int r = 0; r < 4; ++r) {
        float s = 0.f;
        #pragma unroll
        for (int ti = 0; ti < 8; ++ti) {
            const float p = fexp2(g[ti][r]);
            g[ti][r] = p; s += p;
        }
        s += __shfl_xor(s, 1); s += __shfl_xor(s, 2);
        s += __shfl_xor(s, 4); s += __shfl_xor(s, 8);
        inv[r] = frcp(s);
    }
    const int X  = 2*(lid & 7);               // row-dependent unit swizzle
    const int uc = ((4*w + quad) ^ X) << 2;   // u16 offset of this lane's 8B unit
    #pragma unroll
    for (int ti = 0; ti < 8; ++ti) {
        uint2 dv;
        dv.x = cvtpk_rn(g[ti][0]*inv[0], g[ti][1]*inv[1]);
        dv.y = cvtpk_rn(g[ti][2]*inv[2], g[ti][3]*inv[3]);
        *(uint2*)(PT + (ti*16 + lid)*PT_ST + uc) = dv;
    }
}

// PV for t-chunk [32w,+32), K=64 (s-half h), accumulating into c0,c1.
// V fragments hoisted out of the tj2 loop (same address both iterations; CSE-safe).
// P^T read: 16B = unit pair {(8ks+2quad)^X, +1} (X even -> adjacent & aligned).
__device__ __forceinline__ void pv_ctx(const u16* PT, const u16* Vh, int h,
                                       f32x4& c0, f32x4& c1, int w, int lid, int quad)
{
    const int X = 2*(lid & 7);
    const bh8 vb0 = *(const bh8*)(Vh + lid*VH_ST + h*64 +      quad*8);
    const bh8 vb1 = *(const bh8*)(Vh + lid*VH_ST + h*64 + 32 + quad*8);
    #pragma unroll
    for (int tj2 = 0; tj2 < 2; ++tj2) {
        const int tj = 2*w + tj2;
        const bh8 pa0 = *(const bh8*)(PT + (tj*16 + lid)*PT_ST + (((    2*quad) ^ X) << 2));
        const bh8 pa1 = *(const bh8*)(PT + (tj*16 + lid)*PT_ST + (((8 + 2*quad) ^ X) << 2));
        f32x4 acc = tj2 ? c1 : c0;
        acc = MFMA16(pa0, vb0, acc);
        acc = MFMA16(pa1, vb1, acc);
        if (tj2) c1 = acc; else c0 = acc;
    }
}

__global__ __launch_bounds__(256, 4)
void axial_attn_mfma(const float* __restrict__ z, const u16* __restrict__ wsu,
                     float* __restrict__ out)
{
    __shared__ __align__(16) unsigned char lds[LDS_TOT];
    u16* const ptPT = (u16*)(lds + OFF_PT);
    u16* const ptVI = (u16*)(lds + OFF_VIN);
    u16* const ptAh = (u16*)(lds + OFF_AH);
    u16* const ptAl = (u16*)(lds + OFF_AL);
    u16* const ptQP = (u16*)(lds + OFF_QP);
    u16* const ptVH = (u16*)(lds + OFF_VH);

    const int tid = threadIdx.x;
    const int w = tid >> 6, lane = tid & 63, quad = lane >> 4, lid = lane & 15;

    // XCD-aware swizzle: same-XCD blocks cover contiguous xi
    const int blk = blockIdx.x;
    const int j   = blk >> 3;
    const int xi  = ((blk & 7) << 4) | (j & 15);
    const int q   = (j >> 4) & 3;
    const int bi  = j >> 6;
    const int N   = (((bi << 7) | xi) << 2) | q;
    const size_t zbase = (size_t)bi << 20;

    const int c8 = tid >> 5, l5 = tid & 31;        // ch-octet, A-row
    const int vl0 = tid >> 4, vc0 = (tid & 15) << 2;
    const int miQ = w >> 1, niA = (w & 1) * 2;

    // ---- register prefetch of ALL z reads (thread owns 8 consecutive ch) ----
    float a1r[8], a2r[8];
    float4 v4[2];
    {
        const float* s1 = z + zbase + ((size_t)xi << 7) + (q << 5) + l5;
        const float* s2 = z + zbase + (((size_t)(q*32 + l5)) << 7) + xi;
        #pragma unroll
        for (int k = 0; k < 8; ++k)
            a1r[k] = s1[(size_t)(c8*8 + k) << 14];
        const float4* sv = (const float4*)(z + ((size_t)N << 11));
        v4[0] = sv[tid]; v4[1] = sv[tid + 256];
        #pragma unroll
        for (int k = 0; k < 8; ++k)
            a2r[k] = s2[(size_t)(c8*8 + k) << 14];
    }

    // ---- stage A1 (hi/lo, single b128 each) + Vin (RN pair-pack) ----
    {
        u32 hp[4], lp[4];
        #pragma unroll
        for (int k = 0; k < 4; ++k) splitpk(a1r[2*k], a1r[2*k+1], hp[k], lp[k]);
        *(uint4*)(ptAh + l5*AIMG_ST + c8*8) = make_uint4(hp[0], hp[1], hp[2], hp[3]);
        *(uint4*)(ptAl + l5*AIMG_ST + c8*8) = make_uint4(lp[0], lp[1], lp[2], lp[3]);
    }
    #pragma unroll
    for (int k = 0; k < 2; ++k) {
        const float4 vv = v4[k];
        uint2 dv;
        dv.x = cvtpk_rn(vv.x, vv.y);
        dv.y = cvtpk_rn(vv.z, vv.w);
        *(uint2*)(ptVI + (vl0 + 16*k)*AIMG_ST + vc0) = dv;
    }
    __syncthreads();                                            // S1

    gemm_q(ptAh, ptAl, wsu, ptQP, miQ, niA, lid, quad);         // Q1
    gemm_v(ptVI, wsu, ptVH, miQ, niA, lid, quad);               // V (VIN dead after)
    __syncthreads();                                            // S2

    // ---- branch 1 ----
    // stage A2 (Ah/Al dead after Q1; un-aliased from PT) merged into gram0 phase
    {
        u32 hp[4], lp[4];
        #pragma unroll
        for (int k = 0; k < 4; ++k) splitpk(a2r[2*k], a2r[2*k+1], hp[k], lp[k]);
        *(uint4*)(ptAh + l5*AIMG_ST + c8*8) = make_uint4(hp[0], hp[1], hp[2], hp[3]);
        *(uint4*)(ptAl + l5*AIMG_ST + c8*8) = make_uint4(lp[0], lp[1], lp[2], lp[3]);
    }
    f32x4 c10 = {0.f,0.f,0.f,0.f}, c11 = {0.f,0.f,0.f,0.f};
    gram_pt(ptQP, ptPT, 0, w, lid, quad);                       // branch-1 s-half 0
    __syncthreads();                                            // S3 (PT h0 + A2 staged)
    pv_ctx(ptPT, ptVH, 0, c10, c11, w, lid, quad);
    __syncthreads();                                            // S4 (WAR on PT)
    gram_pt(ptQP, ptPT, 1, w, lid, quad);                       // branch-1 s-half 1
    __syncthreads();                                            // S5 (all QP reads done)

    // Q2 (rewrites QP; reads A2 from Ah/Al) merged with pv1 — independent chains
    gemm_q(ptAh, ptAl, wsu, ptQP, miQ, niA, lid, quad);         // Q2
    pv_ctx(ptPT, ptVH, 1, c10, c11, w, lid, quad);
    __syncthreads();                                            // S6 (QP visible; PT reads done)

    // ---- branch 2 ----
    f32x4 c20 = {0.f,0.f,0.f,0.f}, c21 = {0.f,0.f,0.f,0.f};
    gram_pt(ptQP, ptPT, 0, w, lid, quad);                       // branch-2 s-half 0
    __syncthreads();                                            // S7
    pv_ctx(ptPT, ptVH, 0, c20, c21, w, lid, quad);
    __syncthreads();                                            // S8 (WAR on PT)
    gram_pt(ptQP, ptPT, 1, w, lid, quad);                       // branch-2 s-half 1
    __syncthreads();                                            // S9
    pv_ctx(ptPT, ptVH, 1, c20, c21, w, lid, quad);

    // ---- epilogue: out[d=lid][t] = lrelu(ctx1)+lrelu(ctx2), float4 over r ----
    float* ob = out + ((size_t)N << 11) + lid*128;
    #pragma unroll
    for (int tj2 = 0; tj2 < 2; ++tj2) {
        f32x4 a = tj2 ? c11 : c10;
        f32x4 b = tj2 ? c21 : c20;
        float4 ov;
        ov.x = lrelu(a[0]) + lrelu(b[0]);
        ov.y = lrelu(a[1]) + lrelu(b[1]);
        ov.z = lrelu(a[2]) + lrelu(b[2]);
        ov.w = lrelu(a[3]) + lrelu(b[3]);
        *(float4*)(ob + (2*w + tj2)*16 + quad*4) = ov;
    }
}

extern "C" void kernel_launch(void* const* d_in, const int* in_sizes, int n_in,
                              void* d_out, int out_size, void* d_ws, size_t ws_size,
                              hipStream_t stream) {
    const float* z  = (const float*)d_in[0];
    const float* Wq = (const float*)d_in[1];
    const float* Wk = (const float*)d_in[2];
    float* out = (float*)d_out;
    u16* ws = (u16*)d_ws;
    hipLaunchKernelGGL(split_w_kernel, dim3(32), dim3(256), 0, stream, Wq, Wk, ws);
    hipLaunchKernelGGL(axial_attn_mfma, dim3(4096), dim3(256), 0, stream, z, ws, out);
}

// Round 14
// 145.635 us; speedup vs baseline: 1.0635x; 1.0635x over previous
//
#include <hip/hip_runtime.h>

// Fused axial dual-branch attention, bf16 split-precision MFMA. One block per N.
// R17 = R15 + Wq-fragment HOIST (single variable; structure untouched):
//   gemm_q's 8 bh8 Wq frags (same WOFF addrs in Q1 AND Q2) loaded ONCE at the
//   prologue (latency hides under A1/Vin staging) and passed in registers.
//   Removes 8 global loads + vmcnt drain from the HEAD of the Q2 phase (S7->S8
//   convoy critical path) and 8 from Q1. Chain SHORTENED, nothing rearranged.
//   Cost: +32 VGPR (expect ~90-100; 5 waves/EU holds through 102).
// R16 post-mortem: convoy-deletion (11->9 barriers, byte-identical inner code)
//   = 101 µs vs R15's 93 — convoy-count theory FALSIFIED (occupancy unchanged
//   39.5% -> LDS cap didn't bind). Conserved product again (101x11.6~=1172).
//   Falsified levers: LDS traffic (R13), chain restructure (R14), convoys (R16).
//   R12/R15 phase structure is a sharp local optimum; only chain CUTS remain.
// Scored bench flat 154.5±0.7 across R12/R13/R15/R16 (hot 93-101): ~60 µs
//   harness overhead floor; only multi-µs kernel deltas move the score.
// PT: 128 t x 64 s, stride 64 u16; 8B units swizzled u' = u ^ (2*(t&7)).
// Wave w: gram s-tile [64h+16w,+16) -> PT half; PV t-chunk [32w,+32), K=64/half.
// Frags (HW-verified): A[m=lane&15][k=quad*8+j]; B[k=quad*8+j][n=lane&15];
// D row=(lane>>4)*4+reg, col=lane&15.
// Lessons: R5vsR8 occupancy>barriers; R6/R11 don't over-constrain allocator;
// R13 op cuts inside phases don't pay; R14 shuffles ARE LDS ops; R16 barrier
// deletion doesn't pay either.

typedef __attribute__((ext_vector_type(8))) short bh8;
typedef __attribute__((ext_vector_type(4))) float f32x4;
typedef unsigned short u16;
typedef unsigned int u32;

#define MFMA16(a,b,c) __builtin_amdgcn_mfma_f32_16x16x32_bf16(a,b,c,0,0,0)

#define AIMG_ST 72    // u16 (144 B rows)
#define QP_ST   40    // u16 (80 B rows)
#define VH_ST   136   // u16 (272 B rows)
#define PT_ST   64    // u16 (128 B rows, XOR-swizzled 8B units, no pad)

#define OFF_AH   0
#define OFF_AL   4608
#define OFF_VIN  9216
#define OFF_PT   0        // PT (128x64x2=16384) aliases Ah/Al/VIN (disjoint lifetimes)
#define OFF_QP   16384    // 128x40x2 = 10240
#define OFF_VH   26624    // 16x136x2 = 4352
#define LDS_TOT  30976    // x5 blocks = 151.25 KB <= 160 KB -> 5 blocks/CU (LDS-limited)

// ---- fast numeric helpers (guarded HW builtins, safe fallbacks) ----
__device__ __forceinline__ u32 cvtpk_rn(float f0, float f1) {
#if __has_builtin(__builtin_amdgcn_cvt_pk_bf16_f32)
    auto h = __builtin_amdgcn_cvt_pk_bf16_f32(f0, f1);
    u32 r; __builtin_memcpy(&r, &h, sizeof(r)); return r;
#else
    return ((__float_as_uint(f0) + 0x8000u) >> 16) |
           ((__float_as_uint(f1) + 0x8000u) & 0xFFFF0000u);
#endif
}
__device__ __forceinline__ float fexp2(float x) {
#if __has_builtin(__builtin_amdgcn_exp2f)
    return __builtin_amdgcn_exp2f(x);
#else
    return exp2f(x);
#endif
}
__device__ __forceinline__ float frcp(float x) {
#if __has_builtin(__builtin_amdgcn_rcpf)
    return __builtin_amdgcn_rcpf(x);
#else
    return 1.0f / x;
#endif
}
// hi = trunc-bf16 pair (1 v_perm), lo = RN-bf16(residual) pair
__device__ __forceinline__ void splitpk(float f0, float f1, u32& hp, u32& lp) {
    u32 u0 = __float_as_uint(f0), u1 = __float_as_uint(f1);
    hp = __builtin_amdgcn_perm(u1, u0, 0x07060302u);   // [u0.hi16 | u1.hi16]
    float r0 = f0 - __uint_as_float(u0 & 0xFFFF0000u);
    float r1 = f1 - __uint_as_float(u1 & 0xFFFF0000u);
    lp = cvtpk_rn(r0, r1);
}
__device__ __forceinline__ void split3(float f, u16& h, u16& l) {
    u32 u = __float_as_uint(f);
    u32 hf = u & 0xFFFF0000u;
    float r = f - __uint_as_float(hf);
    h = (u16)(hf >> 16);
    l = (u16)((__float_as_uint(r) + 0x8000u) >> 16);
}
__device__ __forceinline__ u16 rnbf(float f) {
    return (u16)((__float_as_uint(f) + 0x8000u) >> 16);
}
__device__ __forceinline__ float lrelu(float x) { return x > 0.f ? x : 0.2f * x; }

// Wq fragments (hoisted once per block; identical for Q1 and Q2)
struct WqFrags { bh8 h0a, h0b, h1a, h1b, l0a, l0b, l1a, l1b; };

// ws u16 layout: [WqH 4096][WqL 4096][WkH 4096][WkL 4096 (unused)]
// Wq pre-scaled by 0.5*sqrt(log2 e) so Gram is natively log2e-scaled for exp2.
__global__ void split_w_kernel(const float* __restrict__ Wq,
                               const float* __restrict__ Wk,
                               u16* __restrict__ ws)
{
    const int i = blockIdx.x * 256 + threadIdx.x;
    const int j = i & 4095;
    const float scale = (i < 4096) ? 0.6005612043932249f : 1.0f;
    const float f = ((i < 4096) ? Wq[j] : Wk[j]) * scale;
    const int base = (i < 4096) ? 0 : 8192;
    u16 h, l; split3(f, h, l);
    ws[base + j] = h;
    ws[base + 4096 + j] = l;
}

#define WOFF(n, ks) (((n)*16 + lid)*64 + (ks)*32 + quad*8)

// Q GEMM: 3-term hi/lo split, 12 MFMA; W frags passed in registers (hoisted).
__device__ __forceinline__ void gemm_q(const WqFrags& W,
                                       const u16* Ah, const u16* Al,
                                       u16* qp, int miQ, int niA, int lid, int quad)
{
    const int offA = (miQ*16 + lid)*AIMG_ST + quad*8;
    bh8 ah0 = *(const bh8*)(Ah + offA);
    bh8 ah1 = *(const bh8*)(Ah + offA + 32);
    bh8 al0 = *(const bh8*)(Al + offA);
    bh8 al1 = *(const bh8*)(Al + offA + 32);
    f32x4 acc0 = {0.f,0.f,0.f,0.f}, acc1 = {0.f,0.f,0.f,0.f};
    acc0 = MFMA16(ah0, W.h0a, acc0); acc0 = MFMA16(ah0, W.l0a, acc0); acc0 = MFMA16(al0, W.h0a, acc0);
    acc0 = MFMA16(ah1, W.h0b, acc0); acc0 = MFMA16(ah1, W.l0b, acc0); acc0 = MFMA16(al1, W.h0b, acc0);
    acc1 = MFMA16(ah0, W.h1a, acc1); acc1 = MFMA16(ah0, W.l1a, acc1); acc1 = MFMA16(al0, W.h1a, acc1);
    acc1 = MFMA16(ah1, W.h1b, acc1); acc1 = MFMA16(ah1, W.l1b, acc1); acc1 = MFMA16(al1, W.h1b, acc1);
    #pragma unroll
    for (int r = 0; r < 4; ++r) {
        const int l = miQ*16 + quad*4 + r;
        const int d = l >> 1;
        const int sbase = (l & 1) << 6;
        const int s0 = sbase + (niA + 0)*16 + lid;
        const int s1 = sbase + (niA + 1)*16 + lid;
        u32 hp, lp;
        splitpk(acc0[r], acc1[r], hp, lp);
        qp[s0*QP_ST + d]      = (u16)hp;
        qp[s0*QP_ST + 16 + d] = (u16)lp;
        qp[s1*QP_ST + d]      = (u16)(hp >> 16);
        qp[s1*QP_ST + 16 + d] = (u16)(lp >> 16);
    }
}

// V GEMM: single-term bf16, 4 MFMA, writes VH[d][s]. (Used once; no hoist value.)
__device__ __forceinline__ void gemm_v(const u16* Vin, const u16* wsu,
                                       u16* vh, int miQ, int niA, int lid, int quad)
{
    const bh8 h0a = *(const bh8*)(wsu + 8192 + WOFF(niA+0,0));
    const bh8 h0b = *(const bh8*)(wsu + 8192 + WOFF(niA+0,1));
    const bh8 h1a = *(const bh8*)(wsu + 8192 + WOFF(niA+1,0));
    const bh8 h1b = *(const bh8*)(wsu + 8192 + WOFF(niA+1,1));
    const int offA = (miQ*16 + lid)*AIMG_ST + quad*8;
    bh8 ah0 = *(const bh8*)(Vin + offA);
    bh8 ah1 = *(const bh8*)(Vin + offA + 32);
    f32x4 acc0 = {0.f,0.f,0.f,0.f}, acc1 = {0.f,0.f,0.f,0.f};
    acc0 = MFMA16(ah0, h0a, acc0); acc0 = MFMA16(ah1, h0b, acc0);
    acc1 = MFMA16(ah0, h1a, acc1); acc1 = MFMA16(ah1, h1b, acc1);
    #pragma unroll
    for (int r = 0; r < 4; ++r) {
        const int l = miQ*16 + quad*4 + r;
        const int d = l >> 1;
        const int sbase = (l & 1) << 6;
        vh[d*VH_ST + sbase + (niA + 0)*16 + lid] = rnbf(acc0[r]);
        vh[d*VH_ST + sbase + (niA + 1)*16 + lid] = rnbf(acc1[r]);
    }
}

// Gram + wave-local softmax (exp2, scale pre-folded) for s-tile [64h+16w, +16).
// P^T write: one 8B unit per (lane,ti), unit index (4w+quad) ^ (2*(t&7)), t&7==lid&7.
__device__ __forceinline__ void gram_pt(const u16* Qp, u16* PT, int h,
                                        int w, int lid, int quad)
{
    const u16* arow = Qp + (h*64 + 16*w + lid)*QP_ST;
    bh8 a1 = *(const bh8*)(arow + quad*8);                        // [Qh;Ql]
    bh8 t  = *(const bh8*)(arow + ((quad >= 2) ? (quad-2)*8 : 0));
    bh8 zz = t ^ t;
    bh8 a2 = (quad < 2) ? zz : t;                                 // [0;Qh]
    f32x4 g[8];
    #pragma unroll
    for (int ti = 0; ti < 8; ++ti) {
        const u16* brow = Qp + (ti*16 + lid)*QP_ST;
        bh8 b1 = *(const bh8*)(brow + (quad & 1)*8);              // [Qh;Qh]
        bh8 b2 = *(const bh8*)(brow + quad*8);                    // [Qh;Ql]
        f32x4 acc = {0.f,0.f,0.f,0.f};
        acc = MFMA16(a1, b1, acc);
        acc = MFMA16(a2, b2, acc);
        g[ti] = acc;
    }
    float inv[4];
    #pragma unroll
    for (int r = 0; r < 4; ++r) {
        float s = 0.f;
        #pragma unroll
        for (int ti = 0; ti < 8; ++ti) {
            const float p = fexp2(g[ti][r]);
            g[ti][r] = p; s += p;
        }
        s += __shfl_xor(s, 1); s += __shfl_xor(s, 2);
        s += __shfl_xor(s, 4); s += __shfl_xor(s, 8);
        inv[r] = frcp(s);
    }
    const int X  = 2*(lid & 7);               // row-dependent unit swizzle
    const int uc = ((4*w + quad) ^ X) << 2;   // u16 offset of this lane's 8B unit
    #pragma unroll
    for (int ti = 0; ti < 8; ++ti) {
        uint2 dv;
        dv.x = cvtpk_rn(g[ti][0]*inv[0], g[ti][1]*inv[1]);
        dv.y = cvtpk_rn(g[ti][2]*inv[2], g[ti][3]*inv[3]);
        *(uint2*)(PT + (ti*16 + lid)*PT_ST + uc) = dv;
    }
}

// PV for t-chunk [32w,+32), K=64 (s-half h), accumulating into c0,c1.
// V fragments hoisted out of the tj2 loop (same address both iterations; CSE-safe).
// P^T read: 16B = unit pair {(8ks+2quad)^X, +1} (X even -> adjacent & aligned).
__device__ __forceinline__ void pv_ctx(const u16* PT, const u16* Vh, int h,
                                       f32x4& c0, f32x4& c1, int w, int lid, int quad)
{
    const int X = 2*(lid & 7);
    const bh8 vb0 = *(const bh8*)(Vh + lid*VH_ST + h*64 +      quad*8);
    const bh8 vb1 = *(const bh8*)(Vh + lid*VH_ST + h*64 + 32 + quad*8);
    #pragma unroll
    for (int tj2 = 0; tj2 < 2; ++tj2) {
        const int tj = 2*w + tj2;
        const bh8 pa0 = *(const bh8*)(PT + (tj*16 + lid)*PT_ST + (((    2*quad) ^ X) << 2));
        const bh8 pa1 = *(const bh8*)(PT + (tj*16 + lid)*PT_ST + (((8 + 2*quad) ^ X) << 2));
        f32x4 acc = tj2 ? c1 : c0;
        acc = MFMA16(pa0, vb0, acc);
        acc = MFMA16(pa1, vb1, acc);
        if (tj2) c1 = acc; else c0 = acc;
    }
}

__global__ __launch_bounds__(256, 4)
void axial_attn_mfma(const float* __restrict__ z, const u16* __restrict__ wsu,
                     float* __restrict__ out)
{
    __shared__ __align__(16) unsigned char lds[LDS_TOT];
    u16* const ptAh = (u16*)(lds + OFF_AH);
    u16* const ptAl = (u16*)(lds + OFF_AL);
    u16* const ptPT = (u16*)(lds + OFF_PT);
    u16* const ptVI = (u16*)(lds + OFF_VIN);
    u16* const ptQP = (u16*)(lds + OFF_QP);
    u16* const ptVH = (u16*)(lds + OFF_VH);

    const int tid = threadIdx.x;
    const int w = tid >> 6, lane = tid & 63, quad = lane >> 4, lid = lane & 15;

    // XCD-aware swizzle: same-XCD blocks cover contiguous xi
    const int blk = blockIdx.x;
    const int j   = blk >> 3;
    const int xi  = ((blk & 7) << 4) | (j & 15);
    const int q   = (j >> 4) & 3;
    const int bi  = j >> 6;
    const int N   = (((bi << 7) | xi) << 2) | q;
    const size_t zbase = (size_t)bi << 20;

    const int c8 = tid >> 5, l5 = tid & 31;        // ch-octet, A-row
    const int vl0 = tid >> 4, vc0 = (tid & 15) << 2;
    const int miQ = w >> 1, niA = (w & 1) * 2;

    // ---- register prefetch of ALL z reads (thread owns 8 consecutive ch) ----
    float a1r[8], a2r[8];
    float4 v4[2];
    {
        const float* s1 = z + zbase + ((size_t)xi << 7) + (q << 5) + l5;
        const float* s2 = z + zbase + (((size_t)(q*32 + l5)) << 7) + xi;
        #pragma unroll
        for (int k = 0; k < 8; ++k)
            a1r[k] = s1[(size_t)(c8*8 + k) << 14];
        const float4* sv = (const float4*)(z + ((size_t)N << 11));
        v4[0] = sv[tid]; v4[1] = sv[tid + 256];
        #pragma unroll
        for (int k = 0; k < 8; ++k)
            a2r[k] = s2[(size_t)(c8*8 + k) << 14];
    }

    // ---- hoisted Wq fragments (used by BOTH Q1 and Q2; latency hides here) ----
    WqFrags wq;
    wq.h0a = *(const bh8*)(wsu +        WOFF(niA+0,0));
    wq.h0b = *(const bh8*)(wsu +        WOFF(niA+0,1));
    wq.h1a = *(const bh8*)(wsu +        WOFF(niA+1,0));
    wq.h1b = *(const bh8*)(wsu +        WOFF(niA+1,1));
    wq.l0a = *(const bh8*)(wsu + 4096 + WOFF(niA+0,0));
    wq.l0b = *(const bh8*)(wsu + 4096 + WOFF(niA+0,1));
    wq.l1a = *(const bh8*)(wsu + 4096 + WOFF(niA+1,0));
    wq.l1b = *(const bh8*)(wsu + 4096 + WOFF(niA+1,1));

    // ---- stage A1 (hi/lo, single b128 each) + Vin (RN pair-pack) ----
    {
        u32 hp[4], lp[4];
        #pragma unroll
        for (int k = 0; k < 4; ++k) splitpk(a1r[2*k], a1r[2*k+1], hp[k], lp[k]);
        *(uint4*)(ptAh + l5*AIMG_ST + c8*8) = make_uint4(hp[0], hp[1], hp[2], hp[3]);
        *(uint4*)(ptAl + l5*AIMG_ST + c8*8) = make_uint4(lp[0], lp[1], lp[2], lp[3]);
    }
    #pragma unroll
    for (int k = 0; k < 2; ++k) {
        const float4 vv = v4[k];
        uint2 dv;
        dv.x = cvtpk_rn(vv.x, vv.y);
        dv.y = cvtpk_rn(vv.z, vv.w);
        *(uint2*)(ptVI + (vl0 + 16*k)*AIMG_ST + vc0) = dv;
    }
    __syncthreads();                                            // S1

    gemm_q(wq, ptAh, ptAl, ptQP, miQ, niA, lid, quad);          // Q1
    gemm_v(ptVI, wsu, ptVH, miQ, niA, lid, quad);               // V
    __syncthreads();                                            // S2

    f32x4 c10 = {0.f,0.f,0.f,0.f}, c11 = {0.f,0.f,0.f,0.f};
    gram_pt(ptQP, ptPT, 0, w, lid, quad);                       // branch-1 s-half 0
    __syncthreads();                                            // S3
    pv_ctx(ptPT, ptVH, 0, c10, c11, w, lid, quad);
    __syncthreads();                                            // S4 (WAR on PT)
    gram_pt(ptQP, ptPT, 1, w, lid, quad);                       // branch-1 s-half 1
    __syncthreads();                                            // S5
    pv_ctx(ptPT, ptVH, 1, c10, c11, w, lid, quad);
    __syncthreads();                                            // S6 (PT reads done)

    // ---- stage A2 (hi/lo, b128) into PT region ----
    {
        u32 hp[4], lp[4];
        #pragma unroll
        for (int k = 0; k < 4; ++k) splitpk(a2r[2*k], a2r[2*k+1], hp[k], lp[k]);
        *(uint4*)(ptAh + l5*AIMG_ST + c8*8) = make_uint4(hp[0], hp[1], hp[2], hp[3]);
        *(uint4*)(ptAl + l5*AIMG_ST + c8*8) = make_uint4(lp[0], lp[1], lp[2], lp[3]);
    }
    __syncthreads();                                            // S7

    gemm_q(wq, ptAh, ptAl, ptQP, miQ, niA, lid, quad);          // Q2 (no reload)
    __syncthreads();                                            // S8

    f32x4 c20 = {0.f,0.f,0.f,0.f}, c21 = {0.f,0.f,0.f,0.f};
    gram_pt(ptQP, ptPT, 0, w, lid, quad);                       // branch-2 s-half 0
    __syncthreads();                                            // S9
    pv_ctx(ptPT, ptVH, 0, c20, c21, w, lid, quad);
    __syncthreads();                                            // S10 (WAR on PT)
    gram_pt(ptQP, ptPT, 1, w, lid, quad);                       // branch-2 s-half 1
    __syncthreads();                                            // S11
    pv_ctx(ptPT, ptVH, 1, c20, c21, w, lid, quad);

    // ---- epilogue: out[d=lid][t] = lrelu(ctx1)+lrelu(ctx2), float4 over r ----
    float* ob = out + ((size_t)N << 11) + lid*128;
    #pragma unroll
    for (int tj2 = 0; tj2 < 2; ++tj2) {
        f32x4 a = tj2 ? c11 : c10;
        f32x4 b = tj2 ? c21 : c20;
        float4 ov;
        ov.x = lrelu(a[0]) + lrelu(b[0]);
        ov.y = lrelu(a[1]) + lrelu(b[1]);
        ov.z = lrelu(a[2]) + lrelu(b[2]);
        ov.w = lrelu(a[3]) + lrelu(b[3]);
        *(float4*)(ob + (2*w + tj2)*16 + quad*4) = ov;
    }
}

extern "C" void kernel_launch(void* const* d_in, const int* in_sizes, int n_in,
                              void* d_out, int out_size, void* d_ws, size_t ws_size,
                              hipStream_t stream) {
    const float* z  = (const float*)d_in[0];
    const float* Wq = (const float*)d_in[1];
    const float* Wk = (const float*)d_in[2];
    float* out = (float*)d_out;
    u16* ws = (u16*)d_ws;
    hipLaunchKernelGGL(split_w_kernel, dim3(32), dim3(256), 0, stream, Wq, Wk, ws);
    hipLaunchKernelGGL(axial_attn_mfma, dim3(4096), dim3(256), 0, stream, z, ws, out);
}

// Round 15
// 143.484 us; speedup vs baseline: 1.0795x; 1.0150x over previous
//
#include <hip/hip_runtime.h>

// Fused axial dual-branch attention, bf16 split-precision MFMA. One block per N.
// R18 = R17 + Wk-fragment HOIST (single variable; structure untouched).
// REFINED MODEL (R17 post-mortem): every __syncthreads drains vmcnt(0), so a
// phase's cost includes a drain equal to the LATENCY OF ITS LATEST GLOBAL LOAD,
// ~independent of load count. R17 (Wq hoist) emptied the Q2 phase of global
// traffic: 93 -> 82-85 µs hot, bench 154.5 -> 145.6 (first scored win).
// The Q1/V phase STILL pays a drain: gemm_v's 4 Wk loads pin S2. Hoist them to
// the prologue (hide under the 16 HBM-strided z loads S1 waits on anyway) ->
// NO phase carries global traffic any more.
// Cost: +16 VGPR nominal (R17's hoist measured +0; expect 60-76).
// Falsified levers: LDS traffic (R13), chain restructure (R14), convoy count
// (R16). Proven lever: phase-head global-load drain removal (R17).
// Conserved product: MfmaUtil x dur ~ 1163-1204 across R12-R17 (MFMA work fixed).
// PT: 128 t x 64 s, stride 64 u16; 8B units swizzled u' = u ^ (2*(t&7)).
// Wave w: gram s-tile [64h+16w,+16) -> PT half; PV t-chunk [32w,+32), K=64/half.
// Frags (HW-verified): A[m=lane&15][k=quad*8+j]; B[k=quad*8+j][n=lane&15];
// D row=(lane>>4)*4+reg, col=lane&15.
// Lessons: R5vsR8 occupancy>barriers; R6/R11 don't over-constrain allocator;
// R13 op cuts inside phases don't pay; R14 shuffles ARE LDS ops; R16 barrier
// deletion doesn't pay; R17 phase-resident global loads DO cost (drain).

typedef __attribute__((ext_vector_type(8))) short bh8;
typedef __attribute__((ext_vector_type(4))) float f32x4;
typedef unsigned short u16;
typedef unsigned int u32;

#define MFMA16(a,b,c) __builtin_amdgcn_mfma_f32_16x16x32_bf16(a,b,c,0,0,0)

#define AIMG_ST 72    // u16 (144 B rows)
#define QP_ST   40    // u16 (80 B rows)
#define VH_ST   136   // u16 (272 B rows)
#define PT_ST   64    // u16 (128 B rows, XOR-swizzled 8B units, no pad)

#define OFF_AH   0
#define OFF_AL   4608
#define OFF_VIN  9216
#define OFF_PT   0        // PT (128x64x2=16384) aliases Ah/Al/VIN (disjoint lifetimes)
#define OFF_QP   16384    // 128x40x2 = 10240
#define OFF_VH   26624    // 16x136x2 = 4352
#define LDS_TOT  30976    // x5 blocks = 151.25 KB <= 160 KB -> 5 blocks/CU (LDS-limited)

// ---- fast numeric helpers (guarded HW builtins, safe fallbacks) ----
__device__ __forceinline__ u32 cvtpk_rn(float f0, float f1) {
#if __has_builtin(__builtin_amdgcn_cvt_pk_bf16_f32)
    auto h = __builtin_amdgcn_cvt_pk_bf16_f32(f0, f1);
    u32 r; __builtin_memcpy(&r, &h, sizeof(r)); return r;
#else
    return ((__float_as_uint(f0) + 0x8000u) >> 16) |
           ((__float_as_uint(f1) + 0x8000u) & 0xFFFF0000u);
#endif
}
__device__ __forceinline__ float fexp2(float x) {
#if __has_builtin(__builtin_amdgcn_exp2f)
    return __builtin_amdgcn_exp2f(x);
#else
    return exp2f(x);
#endif
}
__device__ __forceinline__ float frcp(float x) {
#if __has_builtin(__builtin_amdgcn_rcpf)
    return __builtin_amdgcn_rcpf(x);
#else
    return 1.0f / x;
#endif
}
// hi = trunc-bf16 pair (1 v_perm), lo = RN-bf16(residual) pair
__device__ __forceinline__ void splitpk(float f0, float f1, u32& hp, u32& lp) {
    u32 u0 = __float_as_uint(f0), u1 = __float_as_uint(f1);
    hp = __builtin_amdgcn_perm(u1, u0, 0x07060302u);   // [u0.hi16 | u1.hi16]
    float r0 = f0 - __uint_as_float(u0 & 0xFFFF0000u);
    float r1 = f1 - __uint_as_float(u1 & 0xFFFF0000u);
    lp = cvtpk_rn(r0, r1);
}
__device__ __forceinline__ void split3(float f, u16& h, u16& l) {
    u32 u = __float_as_uint(f);
    u32 hf = u & 0xFFFF0000u;
    float r = f - __uint_as_float(hf);
    h = (u16)(hf >> 16);
    l = (u16)((__float_as_uint(r) + 0x8000u) >> 16);
}
__device__ __forceinline__ u16 rnbf(float f) {
    return (u16)((__float_as_uint(f) + 0x8000u) >> 16);
}
__device__ __forceinline__ float lrelu(float x) { return x > 0.f ? x : 0.2f * x; }

// W fragments (hoisted once per block)
struct WqFrags { bh8 h0a, h0b, h1a, h1b, l0a, l0b, l1a, l1b; };
struct WkFrags { bh8 h0a, h0b, h1a, h1b; };

// ws u16 layout: [WqH 4096][WqL 4096][WkH 4096][WkL 4096 (unused)]
// Wq pre-scaled by 0.5*sqrt(log2 e) so Gram is natively log2e-scaled for exp2.
__global__ void split_w_kernel(const float* __restrict__ Wq,
                               const float* __restrict__ Wk,
                               u16* __restrict__ ws)
{
    const int i = blockIdx.x * 256 + threadIdx.x;
    const int j = i & 4095;
    const float scale = (i < 4096) ? 0.6005612043932249f : 1.0f;
    const float f = ((i < 4096) ? Wq[j] : Wk[j]) * scale;
    const int base = (i < 4096) ? 0 : 8192;
    u16 h, l; split3(f, h, l);
    ws[base + j] = h;
    ws[base + 4096 + j] = l;
}

#define WOFF(n, ks) (((n)*16 + lid)*64 + (ks)*32 + quad*8)

// Q GEMM: 3-term hi/lo split, 12 MFMA; W frags passed in registers (hoisted).
__device__ __forceinline__ void gemm_q(const WqFrags& W,
                                       const u16* Ah, const u16* Al,
                                       u16* qp, int miQ, int niA, int lid, int quad)
{
    const int offA = (miQ*16 + lid)*AIMG_ST + quad*8;
    bh8 ah0 = *(const bh8*)(Ah + offA);
    bh8 ah1 = *(const bh8*)(Ah + offA + 32);
    bh8 al0 = *(const bh8*)(Al + offA);
    bh8 al1 = *(const bh8*)(Al + offA + 32);
    f32x4 acc0 = {0.f,0.f,0.f,0.f}, acc1 = {0.f,0.f,0.f,0.f};
    acc0 = MFMA16(ah0, W.h0a, acc0); acc0 = MFMA16(ah0, W.l0a, acc0); acc0 = MFMA16(al0, W.h0a, acc0);
    acc0 = MFMA16(ah1, W.h0b, acc0); acc0 = MFMA16(ah1, W.l0b, acc0); acc0 = MFMA16(al1, W.h0b, acc0);
    acc1 = MFMA16(ah0, W.h1a, acc1); acc1 = MFMA16(ah0, W.l1a, acc1); acc1 = MFMA16(al0, W.h1a, acc1);
    acc1 = MFMA16(ah1, W.h1b, acc1); acc1 = MFMA16(ah1, W.l1b, acc1); acc1 = MFMA16(al1, W.h1b, acc1);
    #pragma unroll
    for (int r = 0; r < 4; ++r) {
        const int l = miQ*16 + quad*4 + r;
        const int d = l >> 1;
        const int sbase = (l & 1) << 6;
        const int s0 = sbase + (niA + 0)*16 + lid;
        const int s1 = sbase + (niA + 1)*16 + lid;
        u32 hp, lp;
        splitpk(acc0[r], acc1[r], hp, lp);
        qp[s0*QP_ST + d]      = (u16)hp;
        qp[s0*QP_ST + 16 + d] = (u16)lp;
        qp[s1*QP_ST + d]      = (u16)(hp >> 16);
        qp[s1*QP_ST + 16 + d] = (u16)(lp >> 16);
    }
}

// V GEMM: single-term bf16, 4 MFMA; W frags passed in registers (hoisted).
__device__ __forceinline__ void gemm_v(const WkFrags& W,
                                       const u16* Vin,
                                       u16* vh, int miQ, int niA, int lid, int quad)
{
    const int offA = (miQ*16 + lid)*AIMG_ST + quad*8;
    bh8 ah0 = *(const bh8*)(Vin + offA);
    bh8 ah1 = *(const bh8*)(Vin + offA + 32);
    f32x4 acc0 = {0.f,0.f,0.f,0.f}, acc1 = {0.f,0.f,0.f,0.f};
    acc0 = MFMA16(ah0, W.h0a, acc0); acc0 = MFMA16(ah1, W.h0b, acc0);
    acc1 = MFMA16(ah0, W.h1a, acc1); acc1 = MFMA16(ah1, W.h1b, acc1);
    #pragma unroll
    for (int r = 0; r < 4; ++r) {
        const int l = miQ*16 + quad*4 + r;
        const int d = l >> 1;
        const int sbase = (l & 1) << 6;
        vh[d*VH_ST + sbase + (niA + 0)*16 + lid] = rnbf(acc0[r]);
        vh[d*VH_ST + sbase + (niA + 1)*16 + lid] = rnbf(acc1[r]);
    }
}

// Gram + wave-local softmax (exp2, scale pre-folded) for s-tile [64h+16w, +16).
// P^T write: one 8B unit per (lane,ti), unit index (4w+quad) ^ (2*(t&7)), t&7==lid&7.
__device__ __forceinline__ void gram_pt(const u16* Qp, u16* PT, int h,
                                        int w, int lid, int quad)
{
    const u16* arow = Qp + (h*64 + 16*w + lid)*QP_ST;
    bh8 a1 = *(const bh8*)(arow + quad*8);                        // [Qh;Ql]
    bh8 t  = *(const bh8*)(arow + ((quad >= 2) ? (quad-2)*8 : 0));
    bh8 zz = t ^ t;
    bh8 a2 = (quad < 2) ? zz : t;                                 // [0;Qh]
    f32x4 g[8];
    #pragma unroll
    for (int ti = 0; ti < 8; ++ti) {
        const u16* brow = Qp + (ti*16 + lid)*QP_ST;
        bh8 b1 = *(const bh8*)(brow + (quad & 1)*8);              // [Qh;Qh]
        bh8 b2 = *(const bh8*)(brow + quad*8);                    // [Qh;Ql]
        f32x4 acc = {0.f,0.f,0.f,0.f};
        acc = MFMA16(a1, b1, acc);
        acc = MFMA16(a2, b2, acc);
        g[ti] = acc;
    }
    float inv[4];
    #pragma unroll
    for (int r = 0; r < 4; ++r) {
        float s = 0.f;
        #pragma unroll
        for (int ti = 0; ti < 8; ++ti) {
            const float p = fexp2(g[ti][r]);
            g[ti][r] = p; s += p;
        }
        s += __shfl_xor(s, 1); s += __shfl_xor(s, 2);
        s += __shfl_xor(s, 4); s += __shfl_xor(s, 8);
        inv[r] = frcp(s);
    }
    const int X  = 2*(lid & 7);               // row-dependent unit swizzle
    const int uc = ((4*w + quad) ^ X) << 2;   // u16 offset of this lane's 8B unit
    #pragma unroll
    for (int ti = 0; ti < 8; ++ti) {
        uint2 dv;
        dv.x = cvtpk_rn(g[ti][0]*inv[0], g[ti][1]*inv[1]);
        dv.y = cvtpk_rn(g[ti][2]*inv[2], g[ti][3]*inv[3]);
        *(uint2*)(PT + (ti*16 + lid)*PT_ST + uc) = dv;
    }
}

// PV for t-chunk [32w,+32), K=64 (s-half h), accumulating into c0,c1.
// V fragments hoisted out of the tj2 loop (same address both iterations; CSE-safe).
// P^T read: 16B = unit pair {(8ks+2quad)^X, +1} (X even -> adjacent & aligned).
__device__ __forceinline__ void pv_ctx(const u16* PT, const u16* Vh, int h,
                                       f32x4& c0, f32x4& c1, int w, int lid, int quad)
{
    const int X = 2*(lid & 7);
    const bh8 vb0 = *(const bh8*)(Vh + lid*VH_ST + h*64 +      quad*8);
    const bh8 vb1 = *(const bh8*)(Vh + lid*VH_ST + h*64 + 32 + quad*8);
    #pragma unroll
    for (int tj2 = 0; tj2 < 2; ++tj2) {
        const int tj = 2*w + tj2;
        const bh8 pa0 = *(const bh8*)(PT + (tj*16 + lid)*PT_ST + (((    2*quad) ^ X) << 2));
        const bh8 pa1 = *(const bh8*)(PT + (tj*16 + lid)*PT_ST + (((8 + 2*quad) ^ X) << 2));
        f32x4 acc = tj2 ? c1 : c0;
        acc = MFMA16(pa0, vb0, acc);
        acc = MFMA16(pa1, vb1, acc);
        if (tj2) c1 = acc; else c0 = acc;
    }
}

__global__ __launch_bounds__(256, 4)
void axial_attn_mfma(const float* __restrict__ z, const u16* __restrict__ wsu,
                     float* __restrict__ out)
{
    __shared__ __align__(16) unsigned char lds[LDS_TOT];
    u16* const ptAh = (u16*)(lds + OFF_AH);
    u16* const ptAl = (u16*)(lds + OFF_AL);
    u16* const ptPT = (u16*)(lds + OFF_PT);
    u16* const ptVI = (u16*)(lds + OFF_VIN);
    u16* const ptQP = (u16*)(lds + OFF_QP);
    u16* const ptVH = (u16*)(lds + OFF_VH);

    const int tid = threadIdx.x;
    const int w = tid >> 6, lane = tid & 63, quad = lane >> 4, lid = lane & 15;

    // XCD-aware swizzle: same-XCD blocks cover contiguous xi
    const int blk = blockIdx.x;
    const int j   = blk >> 3;
    const int xi  = ((blk & 7) << 4) | (j & 15);
    const int q   = (j >> 4) & 3;
    const int bi  = j >> 6;
    const int N   = (((bi << 7) | xi) << 2) | q;
    const size_t zbase = (size_t)bi << 20;

    const int c8 = tid >> 5, l5 = tid & 31;        // ch-octet, A-row
    const int vl0 = tid >> 4, vc0 = (tid & 15) << 2;
    const int miQ = w >> 1, niA = (w & 1) * 2;

    // ---- register prefetch of ALL z reads (thread owns 8 consecutive ch) ----
    float a1r[8], a2r[8];
    float4 v4[2];
    {
        const float* s1 = z + zbase + ((size_t)xi << 7) + (q << 5) + l5;
        const float* s2 = z + zbase + (((size_t)(q*32 + l5)) << 7) + xi;
        #pragma unroll
        for (int k = 0; k < 8; ++k)
            a1r[k] = s1[(size_t)(c8*8 + k) << 14];
        const float4* sv = (const float4*)(z + ((size_t)N << 11));
        v4[0] = sv[tid]; v4[1] = sv[tid + 256];
        #pragma unroll
        for (int k = 0; k < 8; ++k)
            a2r[k] = s2[(size_t)(c8*8 + k) << 14];
    }

    // ---- hoisted W fragments (Wq: Q1+Q2; Wk: V) — latency hides under z loads ----
    WqFrags wq;
    wq.h0a = *(const bh8*)(wsu +        WOFF(niA+0,0));
    wq.h0b = *(const bh8*)(wsu +        WOFF(niA+0,1));
    wq.h1a = *(const bh8*)(wsu +        WOFF(niA+1,0));
    wq.h1b = *(const bh8*)(wsu +        WOFF(niA+1,1));
    wq.l0a = *(const bh8*)(wsu + 4096 + WOFF(niA+0,0));
    wq.l0b = *(const bh8*)(wsu + 4096 + WOFF(niA+0,1));
    wq.l1a = *(const bh8*)(wsu + 4096 + WOFF(niA+1,0));
    wq.l1b = *(const bh8*)(wsu + 4096 + WOFF(niA+1,1));
    WkFrags wk;
    wk.h0a = *(const bh8*)(wsu + 8192 + WOFF(niA+0,0));
    wk.h0b = *(const bh8*)(wsu + 8192 + WOFF(niA+0,1));
    wk.h1a = *(const bh8*)(wsu + 8192 + WOFF(niA+1,0));
    wk.h1b = *(const bh8*)(wsu + 8192 + WOFF(niA+1,1));

    // ---- stage A1 (hi/lo, single b128 each) + Vin (RN pair-pack) ----
    {
        u32 hp[4], lp[4];
        #pragma unroll
        for (int k = 0; k < 4; ++k) splitpk(a1r[2*k], a1r[2*k+1], hp[k], lp[k]);
        *(uint4*)(ptAh + l5*AIMG_ST + c8*8) = make_uint4(hp[0], hp[1], hp[2], hp[3]);
        *(uint4*)(ptAl + l5*AIMG_ST + c8*8) = make_uint4(lp[0], lp[1], lp[2], lp[3]);
    }
    #pragma unroll
    for (int k = 0; k < 2; ++k) {
        const float4 vv = v4[k];
        uint2 dv;
        dv.x = cvtpk_rn(vv.x, vv.y);
        dv.y = cvtpk_rn(vv.z, vv.w);
        *(uint2*)(ptVI + (vl0 + 16*k)*AIMG_ST + vc0) = dv;
    }
    __syncthreads();                                            // S1

    gemm_q(wq, ptAh, ptAl, ptQP, miQ, niA, lid, quad);          // Q1
    gemm_v(wk, ptVI, ptVH, miQ, niA, lid, quad);                // V (no global loads)
    __syncthreads();                                            // S2

    f32x4 c10 = {0.f,0.f,0.f,0.f}, c11 = {0.f,0.f,0.f,0.f};
    gram_pt(ptQP, ptPT, 0, w, lid, quad);                       // branch-1 s-half 0
    __syncthreads();                                            // S3
    pv_ctx(ptPT, ptVH, 0, c10, c11, w, lid, quad);
    __syncthreads();                                            // S4 (WAR on PT)
    gram_pt(ptQP, ptPT, 1, w, lid, quad);                       // branch-1 s-half 1
    __syncthreads();                                            // S5
    pv_ctx(ptPT, ptVH, 1, c10, c11, w, lid, quad);
    __syncthreads();                                            // S6 (PT reads done)

    // ---- stage A2 (hi/lo, b128) into PT region ----
    {
        u32 hp[4], lp[4];
        #pragma unroll
        for (int k = 0; k < 4; ++k) splitpk(a2r[2*k], a2r[2*k+1], hp[k], lp[k]);
        *(uint4*)(ptAh + l5*AIMG_ST + c8*8) = make_uint4(hp[0], hp[1], hp[2], hp[3]);
        *(uint4*)(ptAl + l5*AIMG_ST + c8*8) = make_uint4(lp[0], lp[1], lp[2], lp[3]);
    }
    __syncthreads();                                            // S7

    gemm_q(wq, ptAh, ptAl, ptQP, miQ, niA, lid, quad);          // Q2 (no reload)
    __syncthreads();                                            // S8

    f32x4 c20 = {0.f,0.f,0.f,0.f}, c21 = {0.f,0.f,0.f,0.f};
    gram_pt(ptQP, ptPT, 0, w, lid, quad);                       // branch-2 s-half 0
    __syncthreads();                                            // S9
    pv_ctx(ptPT, ptVH, 0, c20, c21, w, lid, quad);
    __syncthreads();                                            // S10 (WAR on PT)
    gram_pt(ptQP, ptPT, 1, w, lid, quad);                       // branch-2 s-half 1
    __syncthreads();                                            // S11
    pv_ctx(ptPT, ptVH, 1, c20, c21, w, lid, quad);

    // ---- epilogue: out[d=lid][t] = lrelu(ctx1)+lrelu(ctx2), float4 over r ----
    float* ob = out + ((size_t)N << 11) + lid*128;
    #pragma unroll
    for (int tj2 = 0; tj2 < 2; ++tj2) {
        f32x4 a = tj2 ? c11 : c10;
        f32x4 b = tj2 ? c21 : c20;
        float4 ov;
        ov.x = lrelu(a[0]) + lrelu(b[0]);
        ov.y = lrelu(a[1]) + lrelu(b[1]);
        ov.z = lrelu(a[2]) + lrelu(b[2]);
        ov.w = lrelu(a[3]) + lrelu(b[3]);
        *(float4*)(ob + (2*w + tj2)*16 + quad*4) = ov;
    }
}

extern "C" void kernel_launch(void* const* d_in, const int* in_sizes, int n_in,
                              void* d_out, int out_size, void* d_ws, size_t ws_size,
                              hipStream_t stream) {
    const float* z  = (const float*)d_in[0];
    const float* Wq = (const float*)d_in[1];
    const float* Wk = (const float*)d_in[2];
    float* out = (float*)d_out;
    u16* ws = (u16*)d_ws;
    hipLaunchKernelGGL(split_w_kernel, dim3(32), dim3(256), 0, stream, Wq, Wk, ws);
    hipLaunchKernelGGL(axial_attn_mfma, dim3(4096), dim3(256), 0, stream, z, ws, out);
}

// Round 16
// 142.337 us; speedup vs baseline: 1.0882x; 1.0081x over previous
//
#include <hip/hip_runtime.h>

// Fused axial dual-branch attention, bf16 split-precision MFMA. One block per N.
// R19 = R18 + s_setprio(1) around MFMA clusters (T5; single variable).
// MODEL: every __syncthreads drains vmcnt(0) -> phase-resident global loads cost
// their full latency (R17/R18 removed all: 93 -> ~79 µs hot, bench 155.4->143.5).
// Now no pipe saturated (MFMA 14.5 / VALU 43 / HBM 14) -> distributed issue
// stalls. ~3 blocks/CU at DIFFERENT phases: setprio(1) biases CU issue toward
// MFMA-entering waves (guide T5: +4-7% in exactly this attn regime, m191;
// lockstep GEMM null, m190). Pre-committed: positive->confirmed; null->pivot
// to longer-phase restructure (full-PT K=128, 11->7 barriers).
// Falsified levers: LDS traffic (R13), chain restructure (R14), convoy count
// (R16). Proven: phase-drain removal (R17/R18).
// Conserved product: MfmaUtil x dur ~ 1160-1200 across R12-R18 (MFMA work fixed).
// PT: 128 t x 64 s, stride 64 u16; 8B units swizzled u' = u ^ (2*(t&7)).
// Wave w: gram s-tile [64h+16w,+16) -> PT half; PV t-chunk [32w,+32), K=64/half.
// Frags (HW-verified): A[m=lane&15][k=quad*8+j]; B[k=quad*8+j][n=lane&15];
// D row=(lane>>4)*4+reg, col=lane&15.
// Lessons: R5vsR8 occupancy>barriers; R6/R11 don't over-constrain allocator;
// R13 op cuts inside phases don't pay; R14 shuffles ARE LDS ops; R16 barrier
// deletion doesn't pay; R17/R18 phase-resident global loads DO cost (drain).

typedef __attribute__((ext_vector_type(8))) short bh8;
typedef __attribute__((ext_vector_type(4))) float f32x4;
typedef unsigned short u16;
typedef unsigned int u32;

#define MFMA16(a,b,c) __builtin_amdgcn_mfma_f32_16x16x32_bf16(a,b,c,0,0,0)
#define PRIO1() __builtin_amdgcn_s_setprio(1)
#define PRIO0() __builtin_amdgcn_s_setprio(0)

#define AIMG_ST 72    // u16 (144 B rows)
#define QP_ST   40    // u16 (80 B rows)
#define VH_ST   136   // u16 (272 B rows)
#define PT_ST   64    // u16 (128 B rows, XOR-swizzled 8B units, no pad)

#define OFF_AH   0
#define OFF_AL   4608
#define OFF_VIN  9216
#define OFF_PT   0        // PT (128x64x2=16384) aliases Ah/Al/VIN (disjoint lifetimes)
#define OFF_QP   16384    // 128x40x2 = 10240
#define OFF_VH   26624    // 16x136x2 = 4352
#define LDS_TOT  30976    // x5 blocks = 151.25 KB <= 160 KB -> 5 blocks/CU (LDS-limited)

// ---- fast numeric helpers (guarded HW builtins, safe fallbacks) ----
__device__ __forceinline__ u32 cvtpk_rn(float f0, float f1) {
#if __has_builtin(__builtin_amdgcn_cvt_pk_bf16_f32)
    auto h = __builtin_amdgcn_cvt_pk_bf16_f32(f0, f1);
    u32 r; __builtin_memcpy(&r, &h, sizeof(r)); return r;
#else
    return ((__float_as_uint(f0) + 0x8000u) >> 16) |
           ((__float_as_uint(f1) + 0x8000u) & 0xFFFF0000u);
#endif
}
__device__ __forceinline__ float fexp2(float x) {
#if __has_builtin(__builtin_amdgcn_exp2f)
    return __builtin_amdgcn_exp2f(x);
#else
    return exp2f(x);
#endif
}
__device__ __forceinline__ float frcp(float x) {
#if __has_builtin(__builtin_amdgcn_rcpf)
    return __builtin_amdgcn_rcpf(x);
#else
    return 1.0f / x;
#endif
}
// hi = trunc-bf16 pair (1 v_perm), lo = RN-bf16(residual) pair
__device__ __forceinline__ void splitpk(float f0, float f1, u32& hp, u32& lp) {
    u32 u0 = __float_as_uint(f0), u1 = __float_as_uint(f1);
    hp = __builtin_amdgcn_perm(u1, u0, 0x07060302u);   // [u0.hi16 | u1.hi16]
    float r0 = f0 - __uint_as_float(u0 & 0xFFFF0000u);
    float r1 = f1 - __uint_as_float(u1 & 0xFFFF0000u);
    lp = cvtpk_rn(r0, r1);
}
__device__ __forceinline__ void split3(float f, u16& h, u16& l) {
    u32 u = __float_as_uint(f);
    u32 hf = u & 0xFFFF0000u;
    float r = f - __uint_as_float(hf);
    h = (u16)(hf >> 16);
    l = (u16)((__float_as_uint(r) + 0x8000u) >> 16);
}
__device__ __forceinline__ u16 rnbf(float f) {
    return (u16)((__float_as_uint(f) + 0x8000u) >> 16);
}
__device__ __forceinline__ float lrelu(float x) { return x > 0.f ? x : 0.2f * x; }

// W fragments (hoisted once per block)
struct WqFrags { bh8 h0a, h0b, h1a, h1b, l0a, l0b, l1a, l1b; };
struct WkFrags { bh8 h0a, h0b, h1a, h1b; };

// ws u16 layout: [WqH 4096][WqL 4096][WkH 4096][WkL 4096 (unused)]
// Wq pre-scaled by 0.5*sqrt(log2 e) so Gram is natively log2e-scaled for exp2.
__global__ void split_w_kernel(const float* __restrict__ Wq,
                               const float* __restrict__ Wk,
                               u16* __restrict__ ws)
{
    const int i = blockIdx.x * 256 + threadIdx.x;
    const int j = i & 4095;
    const float scale = (i < 4096) ? 0.6005612043932249f : 1.0f;
    const float f = ((i < 4096) ? Wq[j] : Wk[j]) * scale;
    const int base = (i < 4096) ? 0 : 8192;
    u16 h, l; split3(f, h, l);
    ws[base + j] = h;
    ws[base + 4096 + j] = l;
}

#define WOFF(n, ks) (((n)*16 + lid)*64 + (ks)*32 + quad*8)

// Q GEMM: 3-term hi/lo split, 12 MFMA; W frags passed in registers (hoisted).
__device__ __forceinline__ void gemm_q(const WqFrags& W,
                                       const u16* Ah, const u16* Al,
                                       u16* qp, int miQ, int niA, int lid, int quad)
{
    const int offA = (miQ*16 + lid)*AIMG_ST + quad*8;
    PRIO1();
    bh8 ah0 = *(const bh8*)(Ah + offA);
    bh8 ah1 = *(const bh8*)(Ah + offA + 32);
    bh8 al0 = *(const bh8*)(Al + offA);
    bh8 al1 = *(const bh8*)(Al + offA + 32);
    f32x4 acc0 = {0.f,0.f,0.f,0.f}, acc1 = {0.f,0.f,0.f,0.f};
    acc0 = MFMA16(ah0, W.h0a, acc0); acc0 = MFMA16(ah0, W.l0a, acc0); acc0 = MFMA16(al0, W.h0a, acc0);
    acc0 = MFMA16(ah1, W.h0b, acc0); acc0 = MFMA16(ah1, W.l0b, acc0); acc0 = MFMA16(al1, W.h0b, acc0);
    acc1 = MFMA16(ah0, W.h1a, acc1); acc1 = MFMA16(ah0, W.l1a, acc1); acc1 = MFMA16(al0, W.h1a, acc1);
    acc1 = MFMA16(ah1, W.h1b, acc1); acc1 = MFMA16(ah1, W.l1b, acc1); acc1 = MFMA16(al1, W.h1b, acc1);
    PRIO0();
    #pragma unroll
    for (int r = 0; r < 4; ++r) {
        const int l = miQ*16 + quad*4 + r;
        const int d = l >> 1;
        const int sbase = (l & 1) << 6;
        const int s0 = sbase + (niA + 0)*16 + lid;
        const int s1 = sbase + (niA + 1)*16 + lid;
        u32 hp, lp;
        splitpk(acc0[r], acc1[r], hp, lp);
        qp[s0*QP_ST + d]      = (u16)hp;
        qp[s0*QP_ST + 16 + d] = (u16)lp;
        qp[s1*QP_ST + d]      = (u16)(hp >> 16);
        qp[s1*QP_ST + 16 + d] = (u16)(lp >> 16);
    }
}

// V GEMM: single-term bf16, 4 MFMA; W frags passed in registers (hoisted).
__device__ __forceinline__ void gemm_v(const WkFrags& W,
                                       const u16* Vin,
                                       u16* vh, int miQ, int niA, int lid, int quad)
{
    const int offA = (miQ*16 + lid)*AIMG_ST + quad*8;
    PRIO1();
    bh8 ah0 = *(const bh8*)(Vin + offA);
    bh8 ah1 = *(const bh8*)(Vin + offA + 32);
    f32x4 acc0 = {0.f,0.f,0.f,0.f}, acc1 = {0.f,0.f,0.f,0.f};
    acc0 = MFMA16(ah0, W.h0a, acc0); acc0 = MFMA16(ah1, W.h0b, acc0);
    acc1 = MFMA16(ah0, W.h1a, acc1); acc1 = MFMA16(ah1, W.h1b, acc1);
    PRIO0();
    #pragma unroll
    for (int r = 0; r < 4; ++r) {
        const int l = miQ*16 + quad*4 + r;
        const int d = l >> 1;
        const int sbase = (l & 1) << 6;
        vh[d*VH_ST + sbase + (niA + 0)*16 + lid] = rnbf(acc0[r]);
        vh[d*VH_ST + sbase + (niA + 1)*16 + lid] = rnbf(acc1[r]);
    }
}

// Gram + wave-local softmax (exp2, scale pre-folded) for s-tile [64h+16w, +16).
// P^T write: one 8B unit per (lane,ti), unit index (4w+quad) ^ (2*(t&7)), t&7==lid&7.
__device__ __forceinline__ void gram_pt(const u16* Qp, u16* PT, int h,
                                        int w, int lid, int quad)
{
    const u16* arow = Qp + (h*64 + 16*w + lid)*QP_ST;
    bh8 a1 = *(const bh8*)(arow + quad*8);                        // [Qh;Ql]
    bh8 t  = *(const bh8*)(arow + ((quad >= 2) ? (quad-2)*8 : 0));
    bh8 zz = t ^ t;
    bh8 a2 = (quad < 2) ? zz : t;                                 // [0;Qh]
    f32x4 g[8];
    PRIO1();
    #pragma unroll
    for (int ti = 0; ti < 8; ++ti) {
        const u16* brow = Qp + (ti*16 + lid)*QP_ST;
        bh8 b1 = *(const bh8*)(brow + (quad & 1)*8);              // [Qh;Qh]
        bh8 b2 = *(const bh8*)(brow + quad*8);                    // [Qh;Ql]
        f32x4 acc = {0.f,0.f,0.f,0.f};
        acc = MFMA16(a1, b1, acc);
        acc = MFMA16(a2, b2, acc);
        g[ti] = acc;
    }
    PRIO0();
    float inv[4];
    #pragma unroll
    for (int r = 0; r < 4; ++r) {
        float s = 0.f;
        #pragma unroll
        for (int ti = 0; ti < 8; ++ti) {
            const float p = fexp2(g[ti][r]);
            g[ti][r] = p; s += p;
        }
        s += __shfl_xor(s, 1); s += __shfl_xor(s, 2);
        s += __shfl_xor(s, 4); s += __shfl_xor(s, 8);
        inv[r] = frcp(s);
    }
    const int X  = 2*(lid & 7);               // row-dependent unit swizzle
    const int uc = ((4*w + quad) ^ X) << 2;   // u16 offset of this lane's 8B unit
    #pragma unroll
    for (int ti = 0; ti < 8; ++ti) {
        uint2 dv;
        dv.x = cvtpk_rn(g[ti][0]*inv[0], g[ti][1]*inv[1]);
        dv.y = cvtpk_rn(g[ti][2]*inv[2], g[ti][3]*inv[3]);
        *(uint2*)(PT + (ti*16 + lid)*PT_ST + uc) = dv;
    }
}

// PV for t-chunk [32w,+32), K=64 (s-half h), accumulating into c0,c1.
// V fragments hoisted out of the tj2 loop (same address both iterations; CSE-safe).
// P^T read: 16B = unit pair {(8ks+2quad)^X, +1} (X even -> adjacent & aligned).
__device__ __forceinline__ void pv_ctx(const u16* PT, const u16* Vh, int h,
                                       f32x4& c0, f32x4& c1, int w, int lid, int quad)
{
    const int X = 2*(lid & 7);
    PRIO1();
    const bh8 vb0 = *(const bh8*)(Vh + lid*VH_ST + h*64 +      quad*8);
    const bh8 vb1 = *(const bh8*)(Vh + lid*VH_ST + h*64 + 32 + quad*8);
    #pragma unroll
    for (int tj2 = 0; tj2 < 2; ++tj2) {
        const int tj = 2*w + tj2;
        const bh8 pa0 = *(const bh8*)(PT + (tj*16 + lid)*PT_ST + (((    2*quad) ^ X) << 2));
        const bh8 pa1 = *(const bh8*)(PT + (tj*16 + lid)*PT_ST + (((8 + 2*quad) ^ X) << 2));
        f32x4 acc = tj2 ? c1 : c0;
        acc = MFMA16(pa0, vb0, acc);
        acc = MFMA16(pa1, vb1, acc);
        if (tj2) c1 = acc; else c0 = acc;
    }
    PRIO0();
}

__global__ __launch_bounds__(256, 4)
void axial_attn_mfma(const float* __restrict__ z, const u16* __restrict__ wsu,
                     float* __restrict__ out)
{
    __shared__ __align__(16) unsigned char lds[LDS_TOT];
    u16* const ptAh = (u16*)(lds + OFF_AH);
    u16* const ptAl = (u16*)(lds + OFF_AL);
    u16* const ptPT = (u16*)(lds + OFF_PT);
    u16* const ptVI = (u16*)(lds + OFF_VIN);
    u16* const ptQP = (u16*)(lds + OFF_QP);
    u16* const ptVH = (u16*)(lds + OFF_VH);

    const int tid = threadIdx.x;
    const int w = tid >> 6, lane = tid & 63, quad = lane >> 4, lid = lane & 15;

    // XCD-aware swizzle: same-XCD blocks cover contiguous xi
    const int blk = blockIdx.x;
    const int j   = blk >> 3;
    const int xi  = ((blk & 7) << 4) | (j & 15);
    const int q   = (j >> 4) & 3;
    const int bi  = j >> 6;
    const int N   = (((bi << 7) | xi) << 2) | q;
    const size_t zbase = (size_t)bi << 20;

    const int c8 = tid >> 5, l5 = tid & 31;        // ch-octet, A-row
    const int vl0 = tid >> 4, vc0 = (tid & 15) << 2;
    const int miQ = w >> 1, niA = (w & 1) * 2;

    // ---- register prefetch of ALL z reads (thread owns 8 consecutive ch) ----
    float a1r[8], a2r[8];
    float4 v4[2];
    {
        const float* s1 = z + zbase + ((size_t)xi << 7) + (q << 5) + l5;
        const float* s2 = z + zbase + (((size_t)(q*32 + l5)) << 7) + xi;
        #pragma unroll
        for (int k = 0; k < 8; ++k)
            a1r[k] = s1[(size_t)(c8*8 + k) << 14];
        const float4* sv = (const float4*)(z + ((size_t)N << 11));
        v4[0] = sv[tid]; v4[1] = sv[tid + 256];
        #pragma unroll
        for (int k = 0; k < 8; ++k)
            a2r[k] = s2[(size_t)(c8*8 + k) << 14];
    }

    // ---- hoisted W fragments (Wq: Q1+Q2; Wk: V) — latency hides under z loads ----
    WqFrags wq;
    wq.h0a = *(const bh8*)(wsu +        WOFF(niA+0,0));
    wq.h0b = *(const bh8*)(wsu +        WOFF(niA+0,1));
    wq.h1a = *(const bh8*)(wsu +        WOFF(niA+1,0));
    wq.h1b = *(const bh8*)(wsu +        WOFF(niA+1,1));
    wq.l0a = *(const bh8*)(wsu + 4096 + WOFF(niA+0,0));
    wq.l0b = *(const bh8*)(wsu + 4096 + WOFF(niA+0,1));
    wq.l1a = *(const bh8*)(wsu + 4096 + WOFF(niA+1,0));
    wq.l1b = *(const bh8*)(wsu + 4096 + WOFF(niA+1,1));
    WkFrags wk;
    wk.h0a = *(const bh8*)(wsu + 8192 + WOFF(niA+0,0));
    wk.h0b = *(const bh8*)(wsu + 8192 + WOFF(niA+0,1));
    wk.h1a = *(const bh8*)(wsu + 8192 + WOFF(niA+1,0));
    wk.h1b = *(const bh8*)(wsu + 8192 + WOFF(niA+1,1));

    // ---- stage A1 (hi/lo, single b128 each) + Vin (RN pair-pack) ----
    {
        u32 hp[4], lp[4];
        #pragma unroll
        for (int k = 0; k < 4; ++k) splitpk(a1r[2*k], a1r[2*k+1], hp[k], lp[k]);
        *(uint4*)(ptAh + l5*AIMG_ST + c8*8) = make_uint4(hp[0], hp[1], hp[2], hp[3]);
        *(uint4*)(ptAl + l5*AIMG_ST + c8*8) = make_uint4(lp[0], lp[1], lp[2], lp[3]);
    }
    #pragma unroll
    for (int k = 0; k < 2; ++k) {
        const float4 vv = v4[k];
        uint2 dv;
        dv.x = cvtpk_rn(vv.x, vv.y);
        dv.y = cvtpk_rn(vv.z, vv.w);
        *(uint2*)(ptVI + (vl0 + 16*k)*AIMG_ST + vc0) = dv;
    }
    __syncthreads();                                            // S1

    gemm_q(wq, ptAh, ptAl, ptQP, miQ, niA, lid, quad);          // Q1
    gemm_v(wk, ptVI, ptVH, miQ, niA, lid, quad);                // V (no global loads)
    __syncthreads();                                            // S2

    f32x4 c10 = {0.f,0.f,0.f,0.f}, c11 = {0.f,0.f,0.f,0.f};
    gram_pt(ptQP, ptPT, 0, w, lid, quad);                       // branch-1 s-half 0
    __syncthreads();                                            // S3
    pv_ctx(ptPT, ptVH, 0, c10, c11, w, lid, quad);
    __syncthreads();                                            // S4 (WAR on PT)
    gram_pt(ptQP, ptPT, 1, w, lid, quad);                       // branch-1 s-half 1
    __syncthreads();                                            // S5
    pv_ctx(ptPT, ptVH, 1, c10, c11, w, lid, quad);
    __syncthreads();                                            // S6 (PT reads done)

    // ---- stage A2 (hi/lo, b128) into PT region ----
    {
        u32 hp[4], lp[4];
        #pragma unroll
        for (int k = 0; k < 4; ++k) splitpk(a2r[2*k], a2r[2*k+1], hp[k], lp[k]);
        *(uint4*)(ptAh + l5*AIMG_ST + c8*8) = make_uint4(hp[0], hp[1], hp[2], hp[3]);
        *(uint4*)(ptAl + l5*AIMG_ST + c8*8) = make_uint4(lp[0], lp[1], lp[2], lp[3]);
    }
    __syncthreads();                                            // S7

    gemm_q(wq, ptAh, ptAl, ptQP, miQ, niA, lid, quad);          // Q2 (no reload)
    __syncthreads();                                            // S8

    f32x4 c20 = {0.f,0.f,0.f,0.f}, c21 = {0.f,0.f,0.f,0.f};
    gram_pt(ptQP, ptPT, 0, w, lid, quad);                       // branch-2 s-half 0
    __syncthreads();                                            // S9
    pv_ctx(ptPT, ptVH, 0, c20, c21, w, lid, quad);
    __syncthreads();                                            // S10 (WAR on PT)
    gram_pt(ptQP, ptPT, 1, w, lid, quad);                       // branch-2 s-half 1
    __syncthreads();                                            // S11
    pv_ctx(ptPT, ptVH, 1, c20, c21, w, lid, quad);

    // ---- epilogue: out[d=lid][t] = lrelu(ctx1)+lrelu(ctx2), float4 over r ----
    float* ob = out + ((size_t)N << 11) + lid*128;
    #pragma unroll
    for (int tj2 = 0; tj2 < 2; ++tj2) {
        f32x4 a = tj2 ? c11 : c10;
        f32x4 b = tj2 ? c21 : c20;
        float4 ov;
        ov.x = lrelu(a[0]) + lrelu(b[0]);
        ov.y = lrelu(a[1]) + lrelu(b[1]);
        ov.z = lrelu(a[2]) + lrelu(b[2]);
        ov.w = lrelu(a[3]) + lrelu(b[3]);
        *(float4*)(ob + (2*w + tj2)*16 + quad*4) = ov;
    }
}

extern "C" void kernel_launch(void* const* d_in, const int* in_sizes, int n_in,
                              void* d_out, int out_size, void* d_ws, size_t ws_size,
                              hipStream_t stream) {
    const float* z  = (const float*)d_in[0];
    const float* Wq = (const float*)d_in[1];
    const float* Wk = (const float*)d_in[2];
    float* out = (float*)d_out;
    u16* ws = (u16*)d_ws;
    hipLaunchKernelGGL(split_w_kernel, dim3(32), dim3(256), 0, stream, Wq, Wk, ws);
    hipLaunchKernelGGL(axial_attn_mfma, dim3(4096), dim3(256), 0, stream, z, ws, out);
}